// Round 1
// baseline (1472.938 us; speedup 1.0000x reference)
//
#include <hip/hip_runtime.h>
#include <hip/hip_bf16.h>
#include <math.h>

#define D_MODEL 1024
#define SEQ     2048
#define NB      2
#define NH      16
#define DH      64
#define BHD     (NB*NH)                     // 32
#define ROWS    (NB*SEQ)                    // 4096
#define OUT_ELEMS ((size_t)ROWS*D_MODEL)    // 4194304

// ---------------------------------------------------------------------------
// GEMM: C[4096][1024] = A[4096][1024] @ W[1024][1024]^T (+ optional bias)
// 64x64 tile, 256 threads, 4x4 micro-tile, K-chunk 16, K-major LDS so the
// inner loop is 2x ds_read_b128 + 16 v_fma_f32.
// ---------------------------------------------------------------------------
__global__ __launch_bounds__(256) void gemm_xwt(const float* __restrict__ A,
                                                const float* __restrict__ W,
                                                const float* __restrict__ bias,
                                                float* __restrict__ C)
{
    __shared__ float As[16][68];
    __shared__ float Ws[16][68];
    const int t  = threadIdx.x;
    const int tx = t & 15, ty = t >> 4;
    const int m0 = blockIdx.y << 6;
    const int n0 = blockIdx.x << 6;
    const int lr = t >> 2;            // 0..63  (row within tile)
    const int lc = (t & 3) << 2;      // 0,4,8,12 (k-col within chunk)

    float acc[4][4] = {};
    for (int k0 = 0; k0 < D_MODEL; k0 += 16) {
        float4 av = *(const float4*)&A[(size_t)(m0 + lr)*D_MODEL + k0 + lc];
        float4 wv = *(const float4*)&W[(size_t)(n0 + lr)*D_MODEL + k0 + lc];
        __syncthreads();
        As[lc+0][lr]=av.x; As[lc+1][lr]=av.y; As[lc+2][lr]=av.z; As[lc+3][lr]=av.w;
        Ws[lc+0][lr]=wv.x; Ws[lc+1][lr]=wv.y; Ws[lc+2][lr]=wv.z; Ws[lc+3][lr]=wv.w;
        __syncthreads();
        #pragma unroll
        for (int kk = 0; kk < 16; ++kk) {
            float4 a4 = *(const float4*)&As[kk][ty<<2];
            float4 b4 = *(const float4*)&Ws[kk][tx<<2];
            float a[4] = {a4.x,a4.y,a4.z,a4.w};
            float b[4] = {b4.x,b4.y,b4.z,b4.w};
            #pragma unroll
            for (int i = 0; i < 4; ++i)
                #pragma unroll
                for (int j = 0; j < 4; ++j)
                    acc[i][j] = fmaf(a[i], b[j], acc[i][j]);
        }
    }
    float4 bv = make_float4(0.f, 0.f, 0.f, 0.f);
    if (bias) bv = *(const float4*)&bias[n0 + (tx<<2)];
    #pragma unroll
    for (int i = 0; i < 4; ++i) {
        size_t off = (size_t)(m0 + (ty<<2) + i)*D_MODEL + n0 + (tx<<2);
        float4 o = make_float4(acc[i][0]+bv.x, acc[i][1]+bv.y,
                               acc[i][2]+bv.z, acc[i][3]+bv.w);
        *(float4*)&C[off] = o;
    }
}

// ---------------------------------------------------------------------------
// RoPE in place on q and k.  One thread per (b,s,h,j<32) rotation pair.
// ---------------------------------------------------------------------------
__global__ __launch_bounds__(256) void rope_qk(float* __restrict__ q,
                                               float* __restrict__ k)
{
    int idx = blockIdx.x * 256 + threadIdx.x;    // < NB*SEQ*NH*32 = 2^21
    int j = idx & 31;
    int h = (idx >> 5) & 15;
    int s = (idx >> 9) & 2047;
    int b = idx >> 20;
    // inv_freq = 10000^(-j/32) = exp2(-j * log2(10000)/32)
    float inv_freq = exp2f(-(float)j * 0.41524101186092437f);
    float ang = (float)s * inv_freq;
    float c = cosf(ang), sn = sinf(ang);   // accurate libm (large-arg reduction)
    size_t off = ((size_t)(b*SEQ + s))*D_MODEL + h*DH + j;
    float x1 = q[off], x2 = q[off+32];
    q[off]    = x1*c - x2*sn;
    q[off+32] = x1*sn + x2*c;
    x1 = k[off]; x2 = k[off+32];
    k[off]    = x1*c - x2*sn;
    k[off+32] = x1*sn + x2*c;
}

// ---------------------------------------------------------------------------
// Pass A: per-row online softmax stats (m = row max of scaled scores,
// l = sum exp(s - m)).  Block = (b, h, 64 q-rows); 16 lanes per row.
// ---------------------------------------------------------------------------
__global__ __launch_bounds__(256) void attn_ml(const float* __restrict__ q,
                                               const float* __restrict__ k,
                                               float* __restrict__ mrow,
                                               float* __restrict__ lrow)
{
    __shared__ float qs[DH][68];    // [d][row]  (transposed)
    __shared__ float ks[DH][68];    // [d][krow] (transposed)
    const int t = threadIdx.x, tx = t & 15, ty = t >> 4;
    const int bid = blockIdx.x;
    const int rb = bid & 31, bh = bid >> 5;
    const int b = bh >> 4, h = bh & 15;
    const int row0 = rb << 6;
    const float* qg = q + ((size_t)(b*SEQ) + row0)*D_MODEL + h*DH;
    const float* kg = k + ((size_t)(b*SEQ))*D_MODEL + h*DH;

    #pragma unroll
    for (int u = 0; u < 4; ++u) {
        int idx = u*256 + t;
        int r = idx >> 4, c = (idx & 15) << 2;
        float4 val = *(const float4*)&qg[(size_t)r*D_MODEL + c];
        qs[c+0][r]=val.x; qs[c+1][r]=val.y; qs[c+2][r]=val.z; qs[c+3][r]=val.w;
    }

    float m[4], l[4];
    #pragma unroll
    for (int i = 0; i < 4; ++i) { m[i] = -1e30f; l[i] = 0.f; }

    for (int kt = 0; kt < SEQ; kt += 64) {
        float4 kv[4];
        #pragma unroll
        for (int u = 0; u < 4; ++u) {
            int idx = u*256 + t;
            int r = idx >> 4, c = (idx & 15) << 2;
            kv[u] = *(const float4*)&kg[(size_t)(kt + r)*D_MODEL + c];
        }
        __syncthreads();    // previous tile's readers done
        #pragma unroll
        for (int u = 0; u < 4; ++u) {
            int idx = u*256 + t;
            int r = idx >> 4, c = (idx & 15) << 2;
            ks[c+0][r]=kv[u].x; ks[c+1][r]=kv[u].y; ks[c+2][r]=kv[u].z; ks[c+3][r]=kv[u].w;
        }
        __syncthreads();

        float s[4][4] = {};
        #pragma unroll 16
        for (int kk = 0; kk < DH; ++kk) {
            float4 a4 = *(const float4*)&qs[kk][ty<<2];
            float4 b4 = *(const float4*)&ks[kk][tx<<2];
            float a[4] = {a4.x,a4.y,a4.z,a4.w};
            float bb[4] = {b4.x,b4.y,b4.z,b4.w};
            #pragma unroll
            for (int i = 0; i < 4; ++i)
                #pragma unroll
                for (int j = 0; j < 4; ++j)
                    s[i][j] = fmaf(a[i], bb[j], s[i][j]);
        }
        #pragma unroll
        for (int i = 0; i < 4; ++i) {
            #pragma unroll
            for (int j = 0; j < 4; ++j) s[i][j] *= 0.125f;
            float tm = fmaxf(fmaxf(s[i][0], s[i][1]), fmaxf(s[i][2], s[i][3]));
            tm = fmaxf(tm, __shfl_xor(tm, 1));
            tm = fmaxf(tm, __shfl_xor(tm, 2));
            tm = fmaxf(tm, __shfl_xor(tm, 4));
            tm = fmaxf(tm, __shfl_xor(tm, 8));
            float mnew = fmaxf(m[i], tm);
            float ts = __expf(s[i][0]-mnew) + __expf(s[i][1]-mnew)
                     + __expf(s[i][2]-mnew) + __expf(s[i][3]-mnew);
            ts += __shfl_xor(ts, 1);
            ts += __shfl_xor(ts, 2);
            ts += __shfl_xor(ts, 4);
            ts += __shfl_xor(ts, 8);
            l[i] = l[i]*__expf(m[i]-mnew) + ts;
            m[i] = mnew;
        }
    }
    if (tx == 0) {
        #pragma unroll
        for (int i = 0; i < 4; ++i) {
            int r = row0 + (ty<<2) + i;
            mrow[(size_t)bh*SEQ + r] = m[i];
            lrow[(size_t)bh*SEQ + r] = l[i];
        }
    }
}

// ---------------------------------------------------------------------------
// Pass B: recompute scores, write normalized attn weights to d_out slice,
// accumulate PV into ao.  kws buffer is reused for k^T then w^T.
// ---------------------------------------------------------------------------
__global__ __launch_bounds__(256) void attn_pv(const float* __restrict__ q,
                                               const float* __restrict__ k,
                                               const float* __restrict__ v,
                                               const float* __restrict__ mrow,
                                               const float* __restrict__ lrow,
                                               float* __restrict__ attn,
                                               float* __restrict__ ao)
{
    __shared__ float qs [DH][68];   // [d][row]
    __shared__ float kws[DH][68];   // [d][kcol] for k^T, then [kcol][row] for w^T
    __shared__ float vs [64][68];   // [krow][d] natural
    const int t = threadIdx.x, tx = t & 15, ty = t >> 4;
    const int bid = blockIdx.x;
    const int rb = bid & 31, bh = bid >> 5;
    const int b = bh >> 4, h = bh & 15;
    const int row0 = rb << 6;
    const float* qg = q + ((size_t)(b*SEQ) + row0)*D_MODEL + h*DH;
    const float* kg = k + ((size_t)(b*SEQ))*D_MODEL + h*DH;
    const float* vg = v + ((size_t)(b*SEQ))*D_MODEL + h*DH;

    #pragma unroll
    for (int u = 0; u < 4; ++u) {
        int idx = u*256 + t;
        int r = idx >> 4, c = (idx & 15) << 2;
        float4 val = *(const float4*)&qg[(size_t)r*D_MODEL + c];
        qs[c+0][r]=val.x; qs[c+1][r]=val.y; qs[c+2][r]=val.z; qs[c+3][r]=val.w;
    }

    float mi[4], li[4];
    #pragma unroll
    for (int i = 0; i < 4; ++i) {
        int r = row0 + (ty<<2) + i;
        mi[i] = mrow[(size_t)bh*SEQ + r];
        li[i] = 1.0f / lrow[(size_t)bh*SEQ + r];
    }

    float o[4][4] = {};
    for (int kt = 0; kt < SEQ; kt += 64) {
        float4 kv[4], vv[4];
        #pragma unroll
        for (int u = 0; u < 4; ++u) {
            int idx = u*256 + t;
            int r = idx >> 4, c = (idx & 15) << 2;
            kv[u] = *(const float4*)&kg[(size_t)(kt + r)*D_MODEL + c];
            vv[u] = *(const float4*)&vg[(size_t)(kt + r)*D_MODEL + c];
        }
        __syncthreads();    // prev PV readers done
        #pragma unroll
        for (int u = 0; u < 4; ++u) {
            int idx = u*256 + t;
            int r = idx >> 4, c = (idx & 15) << 2;
            kws[c+0][r]=kv[u].x; kws[c+1][r]=kv[u].y; kws[c+2][r]=kv[u].z; kws[c+3][r]=kv[u].w;
            *(float4*)&vs[r][c] = vv[u];
        }
        __syncthreads();

        float s[4][4] = {};
        #pragma unroll 16
        for (int kk = 0; kk < DH; ++kk) {
            float4 a4 = *(const float4*)&qs[kk][ty<<2];
            float4 b4 = *(const float4*)&kws[kk][tx<<2];
            float a[4] = {a4.x,a4.y,a4.z,a4.w};
            float bb[4] = {b4.x,b4.y,b4.z,b4.w};
            #pragma unroll
            for (int i = 0; i < 4; ++i)
                #pragma unroll
                for (int j = 0; j < 4; ++j)
                    s[i][j] = fmaf(a[i], bb[j], s[i][j]);
        }
        __syncthreads();    // all k^T reads done before overwrite as w^T

        float w[4][4];
        #pragma unroll
        for (int i = 0; i < 4; ++i)
            #pragma unroll
            for (int j = 0; j < 4; ++j)
                w[i][j] = __expf(s[i][j]*0.125f - mi[i]) * li[i];
        #pragma unroll
        for (int i = 0; i < 4; ++i)
            #pragma unroll
            for (int j = 0; j < 4; ++j)
                kws[(tx<<2)+j][(ty<<2)+i] = w[i][j];
        #pragma unroll
        for (int i = 0; i < 4; ++i) {
            size_t off = ((size_t)bh*SEQ + row0 + (ty<<2) + i)*SEQ + kt + (tx<<2);
            *(float4*)&attn[off] = make_float4(w[i][0], w[i][1], w[i][2], w[i][3]);
        }
        __syncthreads();

        #pragma unroll 16
        for (int kk = 0; kk < 64; ++kk) {
            float4 a4 = *(const float4*)&kws[kk][ty<<2];
            float4 b4 = *(const float4*)&vs[kk][tx<<2];
            float a[4] = {a4.x,a4.y,a4.z,a4.w};
            float bb[4] = {b4.x,b4.y,b4.z,b4.w};
            #pragma unroll
            for (int i = 0; i < 4; ++i)
                #pragma unroll
                for (int j = 0; j < 4; ++j)
                    o[i][j] = fmaf(a[i], bb[j], o[i][j]);
        }
    }

    #pragma unroll
    for (int i = 0; i < 4; ++i) {
        size_t off = ((size_t)(b*SEQ) + row0 + (ty<<2) + i)*D_MODEL + h*DH + (tx<<2);
        *(float4*)&ao[off] = make_float4(o[i][0], o[i][1], o[i][2], o[i][3]);
    }
}

// ---------------------------------------------------------------------------
extern "C" void kernel_launch(void* const* d_in, const int* in_sizes, int n_in,
                              void* d_out, int out_size, void* d_ws, size_t ws_size,
                              hipStream_t stream)
{
    const float* query = (const float*)d_in[0];
    const float* key_  = (const float*)d_in[1];
    const float* value = (const float*)d_in[2];
    const float* Wq    = (const float*)d_in[3];
    const float* Wk    = (const float*)d_in[4];
    const float* Wv    = (const float*)d_in[5];
    const float* Wo    = (const float*)d_in[6];
    const float* bo    = (const float*)d_in[7];

    float* out  = (float*)d_out;
    float* attn = out + OUT_ELEMS;

    float* q    = (float*)d_ws;          // 16 MB
    float* k    = q + OUT_ELEMS;         // 16 MB
    float* v    = k + OUT_ELEMS;         // 16 MB
    float* mrow = v + OUT_ELEMS;         // 256 KB
    float* lrow = mrow + (size_t)BHD*SEQ;// 256 KB
    float* ao   = q;                     // alias: pass-B reads its q slice into
                                         // LDS before writing the same slice

    dim3 blk(256);
    dim3 gg(D_MODEL/64, ROWS/64);        // 16 x 64

    hipLaunchKernelGGL(gemm_xwt, gg, blk, 0, stream, query, Wq, nullptr, q);
    hipLaunchKernelGGL(gemm_xwt, gg, blk, 0, stream, key_,  Wk, nullptr, k);
    hipLaunchKernelGGL(gemm_xwt, gg, blk, 0, stream, value, Wv, nullptr, v);
    hipLaunchKernelGGL(rope_qk, dim3((NB*SEQ*NH*32)/256), blk, 0, stream, q, k);
    hipLaunchKernelGGL(attn_ml, dim3(BHD*SEQ/64), blk, 0, stream, q, k, mrow, lrow);
    hipLaunchKernelGGL(attn_pv, dim3(BHD*SEQ/64), blk, 0, stream,
                       q, k, v, mrow, lrow, attn, ao);
    hipLaunchKernelGGL(gemm_xwt, gg, blk, 0, stream, ao, Wo, bo, out);
}

// Round 2
// 481.187 us; speedup vs baseline: 3.0611x; 3.0611x over previous
//
#include <hip/hip_runtime.h>
#include <math.h>

#define D_MODEL 1024
#define SEQ     2048
#define NB      2
#define NH      16
#define DH      64
#define ROWS    (NB*SEQ)                  // 4096
#define OUT_ELEMS ((size_t)ROWS*D_MODEL)  // 4194304

typedef short bf16x8 __attribute__((ext_vector_type(8)));
typedef short bf16x4 __attribute__((ext_vector_type(4)));
typedef float f32x4  __attribute__((ext_vector_type(4)));

__device__ __forceinline__ float bf2f(short u){
    union{float f; unsigned v;} x; x.v = ((unsigned)(unsigned short)u) << 16; return x.f;
}
__device__ __forceinline__ short f2bf(float f){
    union{float f; unsigned v;} x; x.f = f;
    unsigned r = (x.v + 0x7FFF + ((x.v >> 16) & 1)) >> 16;   // RNE
    return (short)r;
}
// XOR swizzles on 16B slots; both write & read sides use the same function.
__device__ __forceinline__ int swz8(int row, int slot){ return slot ^ ((row + (row>>3)) & 7); }
__device__ __forceinline__ int swz4(int row, int slot){ return slot ^ ((row + (row>>2)) & 3); }

#define MFMA16(a,b,c) __builtin_amdgcn_mfma_f32_16x16x32_bf16((a),(b),(c),0,0,0)

// ---------------------------------------------------------------------------
// C[4096|? x1024] = A @ W^T (+bias).  fp32 inputs, fused bf16 conversion in
// staging, MFMA 16x16x32.  128x128 tile, BK=32, 4 waves (each 64x64).
// BF16_OUT=1: C is bf16 (projections).  BF16_OUT=0: C fp32 + bias (final).
// ---------------------------------------------------------------------------
template<int BF16_OUT>
__global__ __launch_bounds__(256) void gemm_bf16(const float* __restrict__ A,
                                                 const float* __restrict__ W,
                                                 const float* __restrict__ bias,
                                                 void* __restrict__ Cout)
{
    __shared__ __align__(16) short Alds[128*32];
    __shared__ __align__(16) short Blds[128*32];
    const int t = threadIdx.x;
    const int lane = t & 63, wid = t >> 6;
    const int m0 = blockIdx.y << 7, n0 = blockIdx.x << 7;
    const int wm = (wid >> 1) << 6, wn = (wid & 1) << 6;
    const int l15 = lane & 15, l4 = lane >> 4;

    f32x4 acc[4][4] = {};

    for (int k0 = 0; k0 < D_MODEL; k0 += 32) {
        float4 ar[4], br[4];
        #pragma unroll
        for (int u = 0; u < 4; ++u) {
            int id = u*256 + t;
            int row = id >> 3, c4 = id & 7;
            ar[u] = *(const float4*)&A[(size_t)(m0+row)*D_MODEL + k0 + c4*4];
            br[u] = *(const float4*)&W[(size_t)(n0+row)*D_MODEL + k0 + c4*4];
        }
        __syncthreads();                       // previous tile fully consumed
        #pragma unroll
        for (int u = 0; u < 4; ++u) {
            int id = u*256 + t;
            int row = id >> 3, c4 = id & 7;
            int off = row*32 + swz4(row, c4>>1)*8 + (c4&1)*4;
            bf16x4 a4 = { f2bf(ar[u].x), f2bf(ar[u].y), f2bf(ar[u].z), f2bf(ar[u].w) };
            bf16x4 b4 = { f2bf(br[u].x), f2bf(br[u].y), f2bf(br[u].z), f2bf(br[u].w) };
            *(bf16x4*)&Alds[off] = a4;
            *(bf16x4*)&Blds[off] = b4;
        }
        __syncthreads();
        bf16x8 af[4], bfr[4];
        #pragma unroll
        for (int mf = 0; mf < 4; ++mf) {
            int row = wm + mf*16 + l15;
            af[mf] = *(const bf16x8*)&Alds[row*32 + swz4(row, l4)*8];
        }
        #pragma unroll
        for (int nf = 0; nf < 4; ++nf) {
            int row = wn + nf*16 + l15;
            bfr[nf] = *(const bf16x8*)&Blds[row*32 + swz4(row, l4)*8];
        }
        #pragma unroll
        for (int mf = 0; mf < 4; ++mf)
            #pragma unroll
            for (int nf = 0; nf < 4; ++nf)
                acc[mf][nf] = MFMA16(af[mf], bfr[nf], acc[mf][nf]);
    }

    // C/D layout: col = lane&15, row = (lane>>4)*4 + j   [m89/m91 verified]
    #pragma unroll
    for (int nf = 0; nf < 4; ++nf) {
        int col = n0 + wn + nf*16 + l15;
        float bv = 0.f;
        if (!BF16_OUT) bv = bias[col];
        #pragma unroll
        for (int mf = 0; mf < 4; ++mf)
            #pragma unroll
            for (int j = 0; j < 4; ++j) {
                int row = m0 + wm + mf*16 + l4*4 + j;
                if (BF16_OUT) ((short*)Cout)[(size_t)row*D_MODEL + col] = f2bf(acc[mf][nf][j]);
                else          ((float*)Cout)[(size_t)row*D_MODEL + col] = acc[mf][nf][j] + bv;
            }
    }
}

// ---------------------------------------------------------------------------
// RoPE in place on bf16 q,k.  One thread = one (b,s,h) row, 8 rotation pairs,
// all loads/stores 16B vectorized.
// ---------------------------------------------------------------------------
__global__ __launch_bounds__(256) void rope_bf16(short* __restrict__ q,
                                                 short* __restrict__ k)
{
    int idx = blockIdx.x*256 + threadIdx.x;        // 262144 threads
    int c = idx & 3, h = (idx >> 2) & 15, bs = idx >> 6;
    int s = bs & (SEQ-1);
    size_t base = (size_t)bs*D_MODEL + h*DH + c*8;
    bf16x8 q1 = *(bf16x8*)&q[base], q2 = *(bf16x8*)&q[base+32];
    bf16x8 k1 = *(bf16x8*)&k[base], k2 = *(bf16x8*)&k[base+32];
    bf16x8 q1o, q2o, k1o, k2o;
    #pragma unroll
    for (int e = 0; e < 8; ++e) {
        int j = c*8 + e;
        // inv_freq = 10000^(-j/32) = 2^(-j*log2(10000)/32)
        float ang = (float)s * exp2f(-(float)j * 0.41524101186092437f);
        float sn, cs; sincosf(ang, &sn, &cs);      // accurate large-arg reduction
        float a = bf2f(q1[e]), b = bf2f(q2[e]);
        q1o[e] = f2bf(a*cs - b*sn); q2o[e] = f2bf(a*sn + b*cs);
        a = bf2f(k1[e]); b = bf2f(k2[e]);
        k1o[e] = f2bf(a*cs - b*sn); k2o[e] = f2bf(a*sn + b*cs);
    }
    *(bf16x8*)&q[base] = q1o; *(bf16x8*)&q[base+32] = q2o;
    *(bf16x8*)&k[base] = k1o; *(bf16x8*)&k[base+32] = k2o;
}

// ---------------------------------------------------------------------------
// Fused two-loop flash attention.  Block = (b,h, 64 q-rows), 4 waves, each
// wave owns 16 q-rows.  Loop 1: MFMA QK^T -> online (m,l).  Loop 2: recompute
// scores, write normalized weights (fp32, d_out slice), P->LDS bf16, MFMA PV.
// K in LDS row-major swizzled; V in LDS TRANSPOSED (Vt[d][k]) swizzled so PV
// B-frags are single ds_read_b128.  All LDS paths <=2-way conflicts.
// ---------------------------------------------------------------------------
__global__ __launch_bounds__(256) void attn_fused(const short* __restrict__ qb,
                                                  const short* __restrict__ kb,
                                                  const short* __restrict__ vb,
                                                  float* __restrict__ attn,
                                                  float* __restrict__ ao)
{
    __shared__ __align__(16) short Klds[64*64];
    __shared__ __align__(16) short Vt  [64*64];
    __shared__ __align__(16) short Plds[4*16*64];   // per-wave private 16x64
    const int t = threadIdx.x, lane = t & 63, wv = t >> 6;
    const int bid = blockIdx.x;
    const int rb = bid & 31, bh = bid >> 5;         // bh = b*16+h
    const int h = bh & 15;
    const size_t bs0 = (size_t)(bh >> 4) * SEQ;
    const int qrow0 = rb << 6;
    const int l15 = lane & 15, l4 = lane >> 4;

    // Q fragments in registers, reused by both loops.
    bf16x8 qf[2];
    {
        int qrow = qrow0 + wv*16 + l15;
        const short* qp = &qb[(bs0 + qrow)*D_MODEL + h*DH + l4*8];
        qf[0] = *(const bf16x8*)&qp[0];
        qf[1] = *(const bf16x8*)&qp[32];
    }

    float m[4] = {-1e30f,-1e30f,-1e30f,-1e30f};
    float l[4] = {0.f, 0.f, 0.f, 0.f};

    // ---- loop 1: final row max + denom --------------------------------
    for (int kt = 0; kt < SEQ; kt += 64) {
        bf16x8 kreg[2];
        #pragma unroll
        for (int u = 0; u < 2; ++u) {
            int id = u*256 + t;
            int row = id >> 3, sl = id & 7;
            kreg[u] = *(const bf16x8*)&kb[(bs0 + kt + row)*D_MODEL + h*DH + sl*8];
        }
        __syncthreads();
        #pragma unroll
        for (int u = 0; u < 2; ++u) {
            int id = u*256 + t;
            int row = id >> 3, sl = id & 7;
            *(bf16x8*)&Klds[row*64 + swz8(row, sl)*8] = kreg[u];
        }
        __syncthreads();
        f32x4 sc[4] = {};
        #pragma unroll
        for (int kk = 0; kk < 2; ++kk)
            #pragma unroll
            for (int nf = 0; nf < 4; ++nf) {
                int krow = nf*16 + l15;
                bf16x8 kf = *(const bf16x8*)&Klds[krow*64 + swz8(krow, kk*4 + l4)*8];
                sc[nf] = MFMA16(qf[kk], kf, sc[nf]);
            }
        #pragma unroll
        for (int j = 0; j < 4; ++j) {
            float v0 = sc[0][j]*0.125f, v1 = sc[1][j]*0.125f,
                  v2 = sc[2][j]*0.125f, v3 = sc[3][j]*0.125f;
            float mx = fmaxf(fmaxf(v0,v1), fmaxf(v2,v3));
            mx = fmaxf(mx, __shfl_xor(mx, 1));
            mx = fmaxf(mx, __shfl_xor(mx, 2));
            mx = fmaxf(mx, __shfl_xor(mx, 4));
            mx = fmaxf(mx, __shfl_xor(mx, 8));
            float mn = fmaxf(m[j], mx);
            float sm = __expf(v0-mn) + __expf(v1-mn) + __expf(v2-mn) + __expf(v3-mn);
            sm += __shfl_xor(sm, 1);
            sm += __shfl_xor(sm, 2);
            sm += __shfl_xor(sm, 4);
            sm += __shfl_xor(sm, 8);
            l[j] = l[j]*__expf(m[j]-mn) + sm;
            m[j] = mn;
        }
    }
    float li[4];
    #pragma unroll
    for (int j = 0; j < 4; ++j) li[j] = 1.0f / l[j];

    // ---- loop 2: weights + PV ------------------------------------------
    f32x4 o[4] = {};
    for (int kt = 0; kt < SEQ; kt += 64) {
        bf16x8 kreg[2], vreg[2];
        #pragma unroll
        for (int u = 0; u < 2; ++u) {
            int id = u*256 + t;
            int row = id >> 3, sl = id & 7;
            kreg[u] = *(const bf16x8*)&kb[(bs0 + kt + row)*D_MODEL + h*DH + sl*8];
            vreg[u] = *(const bf16x8*)&vb[(bs0 + kt + row)*D_MODEL + h*DH + sl*8];
        }
        __syncthreads();                            // prev tile's reads done
        #pragma unroll
        for (int u = 0; u < 2; ++u) {
            int id = u*256 + t;
            int row = id >> 3, sl = id & 7;
            *(bf16x8*)&Klds[row*64 + swz8(row, sl)*8] = kreg[u];
            #pragma unroll
            for (int e = 0; e < 8; ++e) {           // transpose V: Vt[d][k]
                int d = sl*8 + e;
                Vt[d*64 + swz8(d, row>>3)*8 + (row&7)] = vreg[u][e];
            }
        }
        __syncthreads();
        f32x4 sc[4] = {};
        #pragma unroll
        for (int kk = 0; kk < 2; ++kk)
            #pragma unroll
            for (int nf = 0; nf < 4; ++nf) {
                int krow = nf*16 + l15;
                bf16x8 kf = *(const bf16x8*)&Klds[krow*64 + swz8(krow, kk*4 + l4)*8];
                sc[nf] = MFMA16(qf[kk], kf, sc[nf]);
            }
        // normalized weights: global store (fp32) + stash bf16 into Plds
        #pragma unroll
        for (int nf = 0; nf < 4; ++nf) {
            #pragma unroll
            for (int j = 0; j < 4; ++j) {
                float w = __expf(sc[nf][j]*0.125f - m[j]) * li[j];
                int qr = qrow0 + wv*16 + l4*4 + j;
                attn[((size_t)bh*SEQ + qr)*SEQ + kt + nf*16 + l15] = w;
                int prow = l4*4 + j, pcol = nf*16 + l15;
                Plds[wv*1024 + prow*64 + swz8(prow, pcol>>3)*8 + (pcol&7)] = f2bf(w);
            }
        }
        // PV: A = P (wave-private LDS), B = Vt
        #pragma unroll
        for (int kk = 0; kk < 2; ++kk) {
            bf16x8 pa = *(const bf16x8*)&Plds[wv*1024 + l15*64 + swz8(l15, kk*4 + l4)*8];
            #pragma unroll
            for (int nf = 0; nf < 4; ++nf) {
                int d = nf*16 + l15;
                bf16x8 vf = *(const bf16x8*)&Vt[d*64 + swz8(d, kk*4 + l4)*8];
                o[nf] = MFMA16(pa, vf, o[nf]);
            }
        }
    }
    #pragma unroll
    for (int nf = 0; nf < 4; ++nf)
        #pragma unroll
        for (int j = 0; j < 4; ++j) {
            int qr = qrow0 + wv*16 + l4*4 + j;
            ao[(bs0 + qr)*D_MODEL + h*DH + nf*16 + l15] = o[nf][j];
        }
}

// ---------------------------------------------------------------------------
extern "C" void kernel_launch(void* const* d_in, const int* in_sizes, int n_in,
                              void* d_out, int out_size, void* d_ws, size_t ws_size,
                              hipStream_t stream)
{
    const float* query = (const float*)d_in[0];
    const float* key_  = (const float*)d_in[1];
    const float* value = (const float*)d_in[2];
    const float* Wq    = (const float*)d_in[3];
    const float* Wk    = (const float*)d_in[4];
    const float* Wv    = (const float*)d_in[5];
    const float* Wo    = (const float*)d_in[6];
    const float* bo    = (const float*)d_in[7];

    float* out  = (float*)d_out;
    float* attn = out + OUT_ELEMS;

    short* qb = (short*)d_ws;            // 8 MB bf16
    short* kb = qb + OUT_ELEMS;          // 8 MB
    short* vb = kb + OUT_ELEMS;          // 8 MB
    float* ao = (float*)(vb + OUT_ELEMS);// 16 MB fp32

    dim3 blk(256);
    dim3 gg(D_MODEL/128, ROWS/128);      // 8 x 32

    hipLaunchKernelGGL((gemm_bf16<1>), gg, blk, 0, stream, query, Wq, nullptr, (void*)qb);
    hipLaunchKernelGGL((gemm_bf16<1>), gg, blk, 0, stream, key_,  Wk, nullptr, (void*)kb);
    hipLaunchKernelGGL((gemm_bf16<1>), gg, blk, 0, stream, value, Wv, nullptr, (void*)vb);
    hipLaunchKernelGGL(rope_bf16, dim3(ROWS*NH*4/256), blk, 0, stream, qb, kb);
    hipLaunchKernelGGL(attn_fused, dim3(32*32), blk, 0, stream, qb, kb, vb, attn, ao);
    hipLaunchKernelGGL((gemm_bf16<0>), gg, blk, 0, stream, ao, Wo, bo, (void*)out);
}

// Round 3
// 389.823 us; speedup vs baseline: 3.7785x; 1.2344x over previous
//
#include <hip/hip_runtime.h>
#include <math.h>

#define D_MODEL 1024
#define SEQ     2048
#define NB      2
#define NH      16
#define DH      64
#define ROWS    (NB*SEQ)                  // 4096
#define OUT_ELEMS ((size_t)ROWS*D_MODEL)  // 4194304

typedef short bf16x8 __attribute__((ext_vector_type(8)));
typedef short bf16x4 __attribute__((ext_vector_type(4)));
typedef float f32x4  __attribute__((ext_vector_type(4)));

#define AS1 __attribute__((address_space(1)))
#define AS3 __attribute__((address_space(3)))

__device__ __forceinline__ float bf2f(short u){
    union{float f; unsigned v;} x; x.v = ((unsigned)(unsigned short)u) << 16; return x.f;
}
__device__ __forceinline__ short f2bf(float f){
    union{float f; unsigned v;} x; x.f = f;
    unsigned r = (x.v + 0x7FFF + ((x.v >> 16) & 1)) >> 16;   // RNE
    return (short)r;
}
__device__ __forceinline__ int swz8(int row, int slot){ return slot ^ ((row + (row>>3)) & 7); }

#define MFMA16(a,b,c) __builtin_amdgcn_mfma_f32_16x16x32_bf16((a),(b),(c),0,0,0)

// ---------------------------------------------------------------------------
// fp32 -> bf16 convert, one float4 per thread.
// ---------------------------------------------------------------------------
__global__ __launch_bounds__(256) void conv_f2b(const float* __restrict__ in,
                                                short* __restrict__ out)
{
    int i = blockIdx.x*256 + threadIdx.x;
    float4 v = *(const float4*)&in[(size_t)i*4];
    bf16x4 o = { f2bf(v.x), f2bf(v.y), f2bf(v.z), f2bf(v.w) };
    *(bf16x4*)&out[(size_t)i*4] = o;
}

// ---------------------------------------------------------------------------
// Pure-bf16 GEMM (m97 structure): C[4096x1024] = A @ B^T (+bias).
// 128x128 tile, BK=32, 4 waves, global_load_lds width 16, linear LDS.
// BF16_OUT=1: C bf16.  BF16_OUT=0: C fp32 + bias.
// ---------------------------------------------------------------------------
template<int BF16_OUT>
__global__ __launch_bounds__(256) void gemm_bb(const short* __restrict__ A,
                                               const short* __restrict__ B,
                                               const float* __restrict__ bias,
                                               void* __restrict__ Cout)
{
    __shared__ __align__(16) short Alds[128*32];
    __shared__ __align__(16) short Blds[128*32];
    const int t = threadIdx.x, lane = t & 63, wid = t >> 6;
    const int m0 = blockIdx.y << 7, n0 = blockIdx.x << 7;
    const int wm = (wid >> 1) << 6, wn = (wid & 1) << 6;
    const int l15 = lane & 15, l4 = lane >> 4;

    f32x4 acc[4][4] = {};

    for (int k0 = 0; k0 < D_MODEL; k0 += 32) {
        __syncthreads();                   // prev iter's frag reads complete
        #pragma unroll
        for (int u = 0; u < 2; ++u) {
            int row = (wid*2 + u)*16 + (lane >> 2);
            int kc  = k0 + (lane & 3)*8;
            const short* ga = &A[(size_t)(m0 + row)*D_MODEL + kc];
            const short* gb = &B[(size_t)(n0 + row)*D_MODEL + kc];
            __builtin_amdgcn_global_load_lds((const AS1 unsigned*)ga,
                (AS3 unsigned*)&Alds[(wid*2 + u)*512], 16, 0, 0);
            __builtin_amdgcn_global_load_lds((const AS1 unsigned*)gb,
                (AS3 unsigned*)&Blds[(wid*2 + u)*512], 16, 0, 0);
        }
        __syncthreads();                   // vmcnt drain: LDS tile ready
        bf16x8 af[4], bfr[4];
        #pragma unroll
        for (int mf = 0; mf < 4; ++mf)
            af[mf] = *(const bf16x8*)&Alds[(wm + mf*16 + l15)*32 + l4*8];
        #pragma unroll
        for (int nf = 0; nf < 4; ++nf)
            bfr[nf] = *(const bf16x8*)&Blds[(wn + nf*16 + l15)*32 + l4*8];
        #pragma unroll
        for (int mf = 0; mf < 4; ++mf)
            #pragma unroll
            for (int nf = 0; nf < 4; ++nf)
                acc[mf][nf] = MFMA16(af[mf], bfr[nf], acc[mf][nf]);
    }

    // C/D layout: col = lane&15, row = (lane>>4)*4 + j
    #pragma unroll
    for (int nf = 0; nf < 4; ++nf) {
        int col = n0 + wn + nf*16 + l15;
        float bv = 0.f;
        if (!BF16_OUT) bv = bias[col];
        #pragma unroll
        for (int mf = 0; mf < 4; ++mf)
            #pragma unroll
            for (int j = 0; j < 4; ++j) {
                int row = m0 + wm + mf*16 + l4*4 + j;
                if (BF16_OUT) ((short*)Cout)[(size_t)row*D_MODEL + col] = f2bf(acc[mf][nf][j]);
                else          ((float*)Cout)[(size_t)row*D_MODEL + col] = acc[mf][nf][j] + bv;
            }
    }
}

// ---------------------------------------------------------------------------
// RoPE in place on bf16 q,k.  One thread = 8 rotation pairs, 16B vector I/O.
// ---------------------------------------------------------------------------
__global__ __launch_bounds__(256) void rope_bf16(short* __restrict__ q,
                                                 short* __restrict__ k)
{
    int idx = blockIdx.x*256 + threadIdx.x;        // 262144 threads
    int c = idx & 3, h = (idx >> 2) & 15, bs = idx >> 6;
    int s = bs & (SEQ-1);
    size_t base = (size_t)bs*D_MODEL + h*DH + c*8;
    bf16x8 q1 = *(bf16x8*)&q[base], q2 = *(bf16x8*)&q[base+32];
    bf16x8 k1 = *(bf16x8*)&k[base], k2 = *(bf16x8*)&k[base+32];
    bf16x8 q1o, q2o, k1o, k2o;
    #pragma unroll
    for (int e = 0; e < 8; ++e) {
        int j = c*8 + e;
        float ang = (float)s * exp2f(-(float)j * 0.41524101186092437f);
        float sn, cs; sincosf(ang, &sn, &cs);
        float a = bf2f(q1[e]), b = bf2f(q2[e]);
        q1o[e] = f2bf(a*cs - b*sn); q2o[e] = f2bf(a*sn + b*cs);
        a = bf2f(k1[e]); b = bf2f(k2[e]);
        k1o[e] = f2bf(a*cs - b*sn); k2o[e] = f2bf(a*sn + b*cs);
    }
    *(bf16x8*)&q[base] = q1o; *(bf16x8*)&q[base+32] = q2o;
    *(bf16x8*)&k[base] = k1o; *(bf16x8*)&k[base+32] = k2o;
}

// ---------------------------------------------------------------------------
// Fused two-loop flash attention.  Block = (b,h, 128 q-rows), 8 waves, each
// wave owns 16 q-rows.  Loop 1: MFMA QK^T -> online (m,l).  Loop 2: recompute
// scores, write normalized weights (fp32), P->LDS bf16, MFMA PV -> bf16 ao.
// ---------------------------------------------------------------------------
__global__ __launch_bounds__(512) void attn_fused(const short* __restrict__ qb,
                                                  const short* __restrict__ kb,
                                                  const short* __restrict__ vb,
                                                  float* __restrict__ attn,
                                                  short* __restrict__ aob)
{
    __shared__ __align__(16) short Klds[64*64];
    __shared__ __align__(16) short Vt  [64*64];
    __shared__ __align__(16) short Plds[8*16*64];   // per-wave private 16x64
    const int t = threadIdx.x, lane = t & 63, wv = t >> 6;
    const int bid = blockIdx.x;
    const int rb = bid & 15, bh = bid >> 4;          // bh = b*16+h
    const int h = bh & 15;
    const size_t bs0 = (size_t)(bh >> 4) * SEQ;
    const int qrow0 = rb << 7;
    const int l15 = lane & 15, l4 = lane >> 4;
    const int srow = t >> 3, ssl = t & 7;            // staging row/slot

    bf16x8 qf[2];
    {
        int qrow = qrow0 + wv*16 + l15;
        const short* qp = &qb[(bs0 + qrow)*D_MODEL + h*DH + l4*8];
        qf[0] = *(const bf16x8*)&qp[0];
        qf[1] = *(const bf16x8*)&qp[32];
    }

    float m[4] = {-1e30f,-1e30f,-1e30f,-1e30f};
    float l[4] = {0.f, 0.f, 0.f, 0.f};

    // ---- loop 1: final row max + denom ---------------------------------
    for (int kt = 0; kt < SEQ; kt += 64) {
        bf16x8 kreg = *(const bf16x8*)&kb[(bs0 + kt + srow)*D_MODEL + h*DH + ssl*8];
        __syncthreads();
        *(bf16x8*)&Klds[srow*64 + swz8(srow, ssl)*8] = kreg;
        __syncthreads();
        f32x4 sc[4] = {};
        #pragma unroll
        for (int kk = 0; kk < 2; ++kk)
            #pragma unroll
            for (int nf = 0; nf < 4; ++nf) {
                int krow = nf*16 + l15;
                bf16x8 kf = *(const bf16x8*)&Klds[krow*64 + swz8(krow, kk*4 + l4)*8];
                sc[nf] = MFMA16(qf[kk], kf, sc[nf]);
            }
        #pragma unroll
        for (int j = 0; j < 4; ++j) {
            float v0 = sc[0][j]*0.125f, v1 = sc[1][j]*0.125f,
                  v2 = sc[2][j]*0.125f, v3 = sc[3][j]*0.125f;
            float mx = fmaxf(fmaxf(v0,v1), fmaxf(v2,v3));
            mx = fmaxf(mx, __shfl_xor(mx, 1));
            mx = fmaxf(mx, __shfl_xor(mx, 2));
            mx = fmaxf(mx, __shfl_xor(mx, 4));
            mx = fmaxf(mx, __shfl_xor(mx, 8));
            float mn = fmaxf(m[j], mx);
            float sm = __expf(v0-mn) + __expf(v1-mn) + __expf(v2-mn) + __expf(v3-mn);
            sm += __shfl_xor(sm, 1);
            sm += __shfl_xor(sm, 2);
            sm += __shfl_xor(sm, 4);
            sm += __shfl_xor(sm, 8);
            l[j] = l[j]*__expf(m[j]-mn) + sm;
            m[j] = mn;
        }
    }
    float li[4];
    #pragma unroll
    for (int j = 0; j < 4; ++j) li[j] = 1.0f / l[j];

    // ---- loop 2: weights + PV -------------------------------------------
    f32x4 o[4] = {};
    for (int kt = 0; kt < SEQ; kt += 64) {
        bf16x8 kreg = *(const bf16x8*)&kb[(bs0 + kt + srow)*D_MODEL + h*DH + ssl*8];
        bf16x8 vreg = *(const bf16x8*)&vb[(bs0 + kt + srow)*D_MODEL + h*DH + ssl*8];
        __syncthreads();                            // prev tile's reads done
        *(bf16x8*)&Klds[srow*64 + swz8(srow, ssl)*8] = kreg;
        #pragma unroll
        for (int e = 0; e < 8; ++e) {               // transpose V: Vt[d][k]
            int d = ssl*8 + e;
            Vt[d*64 + swz8(d, srow>>3)*8 + (srow&7)] = vreg[e];
        }
        __syncthreads();
        f32x4 sc[4] = {};
        #pragma unroll
        for (int kk = 0; kk < 2; ++kk)
            #pragma unroll
            for (int nf = 0; nf < 4; ++nf) {
                int krow = nf*16 + l15;
                bf16x8 kf = *(const bf16x8*)&Klds[krow*64 + swz8(krow, kk*4 + l4)*8];
                sc[nf] = MFMA16(qf[kk], kf, sc[nf]);
            }
        #pragma unroll
        for (int nf = 0; nf < 4; ++nf) {
            #pragma unroll
            for (int j = 0; j < 4; ++j) {
                float w = __expf(sc[nf][j]*0.125f - m[j]) * li[j];
                int qr = qrow0 + wv*16 + l4*4 + j;
                attn[((size_t)bh*SEQ + qr)*SEQ + kt + nf*16 + l15] = w;
                int prow = l4*4 + j, pcol = nf*16 + l15;
                Plds[wv*1024 + prow*64 + swz8(prow, pcol>>3)*8 + (pcol&7)] = f2bf(w);
            }
        }
        #pragma unroll
        for (int kk = 0; kk < 2; ++kk) {
            bf16x8 pa = *(const bf16x8*)&Plds[wv*1024 + l15*64 + swz8(l15, kk*4 + l4)*8];
            #pragma unroll
            for (int nf = 0; nf < 4; ++nf) {
                int d = nf*16 + l15;
                bf16x8 vf = *(const bf16x8*)&Vt[d*64 + swz8(d, kk*4 + l4)*8];
                o[nf] = MFMA16(pa, vf, o[nf]);
            }
        }
    }
    #pragma unroll
    for (int nf = 0; nf < 4; ++nf)
        #pragma unroll
        for (int j = 0; j < 4; ++j) {
            int qr = qrow0 + wv*16 + l4*4 + j;
            aob[(bs0 + qr)*D_MODEL + h*DH + nf*16 + l15] = f2bf(o[nf][j]);
        }
}

// ---------------------------------------------------------------------------
extern "C" void kernel_launch(void* const* d_in, const int* in_sizes, int n_in,
                              void* d_out, int out_size, void* d_ws, size_t ws_size,
                              hipStream_t stream)
{
    const float* query = (const float*)d_in[0];
    const float* key_  = (const float*)d_in[1];
    const float* value = (const float*)d_in[2];
    const float* Wq    = (const float*)d_in[3];
    const float* Wk    = (const float*)d_in[4];
    const float* Wv    = (const float*)d_in[5];
    const float* Wo    = (const float*)d_in[6];
    const float* bo    = (const float*)d_in[7];

    float* out  = (float*)d_out;
    float* attn = out + OUT_ELEMS;

    // ws layout (shorts): xbuf 4M | wq 1M | wk 1M | wv 1M | wo 1M | qb 4M | kb 4M | vb 4M
    short* xbuf = (short*)d_ws;                 // 8 MB bounce (query/key/value), later aob
    short* wqb  = xbuf + OUT_ELEMS;
    short* wkb  = wqb + (size_t)D_MODEL*D_MODEL;
    short* wvb  = wkb + (size_t)D_MODEL*D_MODEL;
    short* wob  = wvb + (size_t)D_MODEL*D_MODEL;
    short* qb   = wob + (size_t)D_MODEL*D_MODEL;
    short* kb   = qb + OUT_ELEMS;
    short* vb   = kb + OUT_ELEMS;
    short* aob  = xbuf;                          // alias: xbuf dead after gemm3

    dim3 blk(256);
    dim3 gg(D_MODEL/128, ROWS/128);              // 8 x 32
    const int W4 = (D_MODEL*D_MODEL)/4/256;      // 1024 blocks
    const int X4 = (int)(OUT_ELEMS/4/256);       // 4096 blocks

    hipLaunchKernelGGL(conv_f2b, dim3(W4), blk, 0, stream, Wq, wqb);
    hipLaunchKernelGGL(conv_f2b, dim3(W4), blk, 0, stream, Wk, wkb);
    hipLaunchKernelGGL(conv_f2b, dim3(W4), blk, 0, stream, Wv, wvb);
    hipLaunchKernelGGL(conv_f2b, dim3(W4), blk, 0, stream, Wo, wob);

    hipLaunchKernelGGL(conv_f2b, dim3(X4), blk, 0, stream, query, xbuf);
    hipLaunchKernelGGL((gemm_bb<1>), gg, blk, 0, stream, xbuf, wqb, (const float*)nullptr, (void*)qb);
    hipLaunchKernelGGL(conv_f2b, dim3(X4), blk, 0, stream, key_, xbuf);
    hipLaunchKernelGGL((gemm_bb<1>), gg, blk, 0, stream, xbuf, wkb, (const float*)nullptr, (void*)kb);
    hipLaunchKernelGGL(conv_f2b, dim3(X4), blk, 0, stream, value, xbuf);
    hipLaunchKernelGGL((gemm_bb<1>), gg, blk, 0, stream, xbuf, wvb, (const float*)nullptr, (void*)vb);

    hipLaunchKernelGGL(rope_bf16, dim3(ROWS*NH*4/256), blk, 0, stream, qb, kb);
    hipLaunchKernelGGL(attn_fused, dim3(16*32), dim3(512), 0, stream, qb, kb, vb, attn, aob);
    hipLaunchKernelGGL((gemm_bb<0>), gg, blk, 0, stream, aob, wob, bo, (void*)out);
}

// Round 4
// 332.764 us; speedup vs baseline: 4.4264x; 1.1715x over previous
//
#include <hip/hip_runtime.h>
#include <math.h>

#define D_MODEL 1024
#define SEQ     2048
#define NB      2
#define NH      16
#define DH      64
#define ROWS    (NB*SEQ)                  // 4096
#define OUT_ELEMS ((size_t)ROWS*D_MODEL)  // 4194304

typedef short bf16x8 __attribute__((ext_vector_type(8)));
typedef short bf16x4 __attribute__((ext_vector_type(4)));
typedef float f32x4  __attribute__((ext_vector_type(4)));

#define AS1 __attribute__((address_space(1)))
#define AS3 __attribute__((address_space(3)))

__device__ __forceinline__ float bf2f(short u){
    union{float f; unsigned v;} x; x.v = ((unsigned)(unsigned short)u) << 16; return x.f;
}
__device__ __forceinline__ short f2bf(float f){
    union{float f; unsigned v;} x; x.f = f;
    unsigned r = (x.v + 0x7FFF + ((x.v >> 16) & 1)) >> 16;   // RNE
    return (short)r;
}
__device__ __forceinline__ int swz8(int row, int slot){ return slot ^ ((row + (row>>3)) & 7); }

#define MFMA16(a,b,c) __builtin_amdgcn_mfma_f32_16x16x32_bf16((a),(b),(c),0,0,0)

// ---------------------------------------------------------------------------
// Convert all 4 weight matrices fp32->bf16 in one kernel.
// ---------------------------------------------------------------------------
__global__ __launch_bounds__(256) void conv_w(const float* __restrict__ Wq,
                                              const float* __restrict__ Wk,
                                              const float* __restrict__ Wv,
                                              const float* __restrict__ Wo,
                                              short* __restrict__ wqkv,
                                              short* __restrict__ wob)
{
    int i = blockIdx.x*256 + threadIdx.x;        // 1048576 float4 units
    int sel = i >> 18;                           // 262144 per weight
    int loc = i & 262143;
    const float* src = sel==0 ? Wq : sel==1 ? Wk : sel==2 ? Wv : Wo;
    short* dst = sel < 3 ? wqkv + (size_t)sel*1048576 : wob;
    float4 v = *(const float4*)&src[(size_t)loc*4];
    bf16x4 o = { f2bf(v.x), f2bf(v.y), f2bf(v.z), f2bf(v.w) };
    *(bf16x4*)&dst[(size_t)loc*4] = o;
}

// ---------------------------------------------------------------------------
// RoPE cos/sin table: tab[s*64 + j*2] = cos, +1 = sin  (s<2048, j<32).
// ---------------------------------------------------------------------------
__global__ __launch_bounds__(256) void rope_table(float* __restrict__ tab)
{
    int i = blockIdx.x*256 + threadIdx.x;        // 65536
    int j = i & 31, s = i >> 5;
    float ang = (float)s * exp2f(-(float)j * 0.41524101186092437f);
    float sn, cs; sincosf(ang, &sn, &cs);        // accurate large-arg reduction
    tab[(size_t)s*64 + j*2]     = cs;
    tab[(size_t)s*64 + j*2 + 1] = sn;
}

// ---------------------------------------------------------------------------
// Fused QKV projection: z in {0,1,2} selects (query,Wq)->qb, (key,Wk)->kb,
// (value,Wv)->vb.  A fp32 reg-staged with fused bf16 convert; B (bf16)
// global_load_lds width 16.  128x128 tile, BK=32, 4 waves.  768 blocks.
// ---------------------------------------------------------------------------
__global__ __launch_bounds__(256) void gemm_qkv(const float* __restrict__ qx,
                                                const float* __restrict__ kx,
                                                const float* __restrict__ vx,
                                                const short* __restrict__ wqkv,
                                                short* __restrict__ qkvb)
{
    const int z = blockIdx.z;
    const float* A = z==0 ? qx : z==1 ? kx : vx;
    const short* B = wqkv + (size_t)z*D_MODEL*D_MODEL;
    short*       C = qkvb + (size_t)z*OUT_ELEMS;

    __shared__ __align__(16) short Alds[128*32];
    __shared__ __align__(16) short Blds[128*32];
    const int t = threadIdx.x, lane = t & 63, wid = t >> 6;
    const int m0 = blockIdx.y << 7, n0 = blockIdx.x << 7;
    const int wm = (wid >> 1) << 6, wn = (wid & 1) << 6;
    const int l15 = lane & 15, l4 = lane >> 4;

    f32x4 acc[4][4] = {};

    for (int k0 = 0; k0 < D_MODEL; k0 += 32) {
        float4 ar[4];
        #pragma unroll
        for (int u = 0; u < 4; ++u) {
            int id = u*256 + t;
            int row = id >> 3, c4 = id & 7;
            ar[u] = *(const float4*)&A[(size_t)(m0+row)*D_MODEL + k0 + c4*4];
        }
        __syncthreads();                   // prev iter's frag reads complete
        #pragma unroll
        for (int u = 0; u < 4; ++u) {
            int id = u*256 + t;
            int row = id >> 3, c4 = id & 7;
            bf16x4 a4 = { f2bf(ar[u].x), f2bf(ar[u].y), f2bf(ar[u].z), f2bf(ar[u].w) };
            *(bf16x4*)&Alds[row*32 + c4*4] = a4;
        }
        #pragma unroll
        for (int u = 0; u < 2; ++u) {
            int row = (wid*2 + u)*16 + (lane >> 2);
            int kc  = k0 + (lane & 3)*8;
            const short* gb = &B[(size_t)(n0 + row)*D_MODEL + kc];
            __builtin_amdgcn_global_load_lds((const AS1 unsigned*)gb,
                (AS3 unsigned*)&Blds[(wid*2 + u)*512], 16, 0, 0);
        }
        __syncthreads();                   // lgkm + vmcnt drain: tile ready
        bf16x8 af[4], bfr[4];
        #pragma unroll
        for (int mf = 0; mf < 4; ++mf)
            af[mf] = *(const bf16x8*)&Alds[(wm + mf*16 + l15)*32 + l4*8];
        #pragma unroll
        for (int nf = 0; nf < 4; ++nf)
            bfr[nf] = *(const bf16x8*)&Blds[(wn + nf*16 + l15)*32 + l4*8];
        #pragma unroll
        for (int mf = 0; mf < 4; ++mf)
            #pragma unroll
            for (int nf = 0; nf < 4; ++nf)
                acc[mf][nf] = MFMA16(af[mf], bfr[nf], acc[mf][nf]);
    }

    #pragma unroll
    for (int nf = 0; nf < 4; ++nf) {
        int col = n0 + wn + nf*16 + l15;
        #pragma unroll
        for (int mf = 0; mf < 4; ++mf)
            #pragma unroll
            for (int j = 0; j < 4; ++j) {
                int row = m0 + wm + mf*16 + l4*4 + j;
                C[(size_t)row*D_MODEL + col] = f2bf(acc[mf][nf][j]);
            }
    }
}

// ---------------------------------------------------------------------------
// Pure-bf16 GEMM for the output projection: out = aob @ wob^T + bo (fp32 out).
// ---------------------------------------------------------------------------
__global__ __launch_bounds__(256) void gemm_out(const short* __restrict__ A,
                                                const short* __restrict__ B,
                                                const float* __restrict__ bias,
                                                float* __restrict__ Cout)
{
    __shared__ __align__(16) short Alds[128*32];
    __shared__ __align__(16) short Blds[128*32];
    const int t = threadIdx.x, lane = t & 63, wid = t >> 6;
    const int m0 = blockIdx.y << 7, n0 = blockIdx.x << 7;
    const int wm = (wid >> 1) << 6, wn = (wid & 1) << 6;
    const int l15 = lane & 15, l4 = lane >> 4;

    f32x4 acc[4][4] = {};

    for (int k0 = 0; k0 < D_MODEL; k0 += 32) {
        __syncthreads();
        #pragma unroll
        for (int u = 0; u < 2; ++u) {
            int row = (wid*2 + u)*16 + (lane >> 2);
            int kc  = k0 + (lane & 3)*8;
            const short* ga = &A[(size_t)(m0 + row)*D_MODEL + kc];
            const short* gb = &B[(size_t)(n0 + row)*D_MODEL + kc];
            __builtin_amdgcn_global_load_lds((const AS1 unsigned*)ga,
                (AS3 unsigned*)&Alds[(wid*2 + u)*512], 16, 0, 0);
            __builtin_amdgcn_global_load_lds((const AS1 unsigned*)gb,
                (AS3 unsigned*)&Blds[(wid*2 + u)*512], 16, 0, 0);
        }
        __syncthreads();
        bf16x8 af[4], bfr[4];
        #pragma unroll
        for (int mf = 0; mf < 4; ++mf)
            af[mf] = *(const bf16x8*)&Alds[(wm + mf*16 + l15)*32 + l4*8];
        #pragma unroll
        for (int nf = 0; nf < 4; ++nf)
            bfr[nf] = *(const bf16x8*)&Blds[(wn + nf*16 + l15)*32 + l4*8];
        #pragma unroll
        for (int mf = 0; mf < 4; ++mf)
            #pragma unroll
            for (int nf = 0; nf < 4; ++nf)
                acc[mf][nf] = MFMA16(af[mf], bfr[nf], acc[mf][nf]);
    }

    #pragma unroll
    for (int nf = 0; nf < 4; ++nf) {
        int col = n0 + wn + nf*16 + l15;
        float bv = bias[col];
        #pragma unroll
        for (int mf = 0; mf < 4; ++mf)
            #pragma unroll
            for (int j = 0; j < 4; ++j) {
                int row = m0 + wm + mf*16 + l4*4 + j;
                Cout[(size_t)row*D_MODEL + col] = acc[mf][nf][j] + bv;
            }
    }
}

// ---------------------------------------------------------------------------
// RoPE in place on bf16 q,k using the precomputed table.
// ---------------------------------------------------------------------------
__global__ __launch_bounds__(256) void rope_apply(short* __restrict__ q,
                                                  short* __restrict__ k,
                                                  const float* __restrict__ tab)
{
    int idx = blockIdx.x*256 + threadIdx.x;        // 262144 threads
    int c = idx & 3, h = (idx >> 2) & 15, bs = idx >> 6;
    int s = bs & (SEQ-1);
    size_t base = (size_t)bs*D_MODEL + h*DH + c*8;
    const float4* tp = (const float4*)&tab[(size_t)s*64 + c*16];
    float4 t0 = tp[0], t1 = tp[1], t2 = tp[2], t3 = tp[3];
    float cs[8] = {t0.x,t0.z,t1.x,t1.z,t2.x,t2.z,t3.x,t3.z};
    float sn[8] = {t0.y,t0.w,t1.y,t1.w,t2.y,t2.w,t3.y,t3.w};
    bf16x8 q1 = *(bf16x8*)&q[base], q2 = *(bf16x8*)&q[base+32];
    bf16x8 k1 = *(bf16x8*)&k[base], k2 = *(bf16x8*)&k[base+32];
    bf16x8 q1o, q2o, k1o, k2o;
    #pragma unroll
    for (int e = 0; e < 8; ++e) {
        float a = bf2f(q1[e]), b = bf2f(q2[e]);
        q1o[e] = f2bf(a*cs[e] - b*sn[e]); q2o[e] = f2bf(a*sn[e] + b*cs[e]);
        a = bf2f(k1[e]); b = bf2f(k2[e]);
        k1o[e] = f2bf(a*cs[e] - b*sn[e]); k2o[e] = f2bf(a*sn[e] + b*cs[e]);
    }
    *(bf16x8*)&q[base] = q1o; *(bf16x8*)&q[base+32] = q2o;
    *(bf16x8*)&k[base] = k1o; *(bf16x8*)&k[base+32] = k2o;
}

// ---------------------------------------------------------------------------
// Fused two-loop flash attention.  Block = (b,h, 128 q-rows), 8 waves.
// T1 XCD swizzle, T14 reg double-buffered staging, T5 setprio on MFMA,
// nontemporal streamed weight stores.
// ---------------------------------------------------------------------------
__global__ __launch_bounds__(512) void attn_fused(const short* __restrict__ qb,
                                                  const short* __restrict__ kb,
                                                  const short* __restrict__ vb,
                                                  float* __restrict__ attn,
                                                  short* __restrict__ aob)
{
    __shared__ __align__(16) short Klds[64*64];
    __shared__ __align__(16) short Vt  [64*64];
    __shared__ __align__(16) short Plds[8*16*64];
    const int t = threadIdx.x, lane = t & 63, wv = t >> 6;
    const int bid = blockIdx.x;
    const int nb = (bid & 7)*64 + (bid >> 3);       // XCD swizzle (512 = 8*64)
    const int rb = nb & 15, bh = nb >> 4;           // bh = b*16+h
    const int h = bh & 15;
    const size_t bs0 = (size_t)(bh >> 4) * SEQ;
    const int qrow0 = rb << 7;
    const int l15 = lane & 15, l4 = lane >> 4;
    const int srow = t >> 3, ssl = t & 7;           // staging row/slot

    bf16x8 qf[2];
    {
        int qrow = qrow0 + wv*16 + l15;
        const short* qp = &qb[(bs0 + qrow)*D_MODEL + h*DH + l4*8];
        qf[0] = *(const bf16x8*)&qp[0];
        qf[1] = *(const bf16x8*)&qp[32];
    }

    const short* kbase = &kb[(bs0 + srow)*D_MODEL + h*DH + ssl*8];
    const short* vbase = &vb[(bs0 + srow)*D_MODEL + h*DH + ssl*8];

    float m[4] = {-1e30f,-1e30f,-1e30f,-1e30f};
    float l[4] = {0.f, 0.f, 0.f, 0.f};

    // ---- loop 1: final row max + denom ---------------------------------
    bf16x8 kreg = *(const bf16x8*)&kbase[0];
    for (int kt = 0; kt < SEQ; kt += 64) {
        __syncthreads();                            // prev tile's reads done
        *(bf16x8*)&Klds[srow*64 + swz8(srow, ssl)*8] = kreg;
        __syncthreads();
        if (kt + 64 < SEQ)
            kreg = *(const bf16x8*)&kbase[(size_t)(kt+64)*D_MODEL];
        f32x4 sc[4] = {};
        __builtin_amdgcn_s_setprio(1);
        #pragma unroll
        for (int kk = 0; kk < 2; ++kk)
            #pragma unroll
            for (int nf = 0; nf < 4; ++nf) {
                int krow = nf*16 + l15;
                bf16x8 kf = *(const bf16x8*)&Klds[krow*64 + swz8(krow, kk*4 + l4)*8];
                sc[nf] = MFMA16(qf[kk], kf, sc[nf]);
            }
        __builtin_amdgcn_s_setprio(0);
        #pragma unroll
        for (int j = 0; j < 4; ++j) {
            float v0 = sc[0][j]*0.125f, v1 = sc[1][j]*0.125f,
                  v2 = sc[2][j]*0.125f, v3 = sc[3][j]*0.125f;
            float mx = fmaxf(fmaxf(v0,v1), fmaxf(v2,v3));
            mx = fmaxf(mx, __shfl_xor(mx, 1));
            mx = fmaxf(mx, __shfl_xor(mx, 2));
            mx = fmaxf(mx, __shfl_xor(mx, 4));
            mx = fmaxf(mx, __shfl_xor(mx, 8));
            float mn = fmaxf(m[j], mx);
            float sm = __expf(v0-mn) + __expf(v1-mn) + __expf(v2-mn) + __expf(v3-mn);
            sm += __shfl_xor(sm, 1);
            sm += __shfl_xor(sm, 2);
            sm += __shfl_xor(sm, 4);
            sm += __shfl_xor(sm, 8);
            l[j] = l[j]*__expf(m[j]-mn) + sm;
            m[j] = mn;
        }
    }
    float li[4];
    #pragma unroll
    for (int j = 0; j < 4; ++j) li[j] = 1.0f / l[j];

    // ---- loop 2: weights + PV -------------------------------------------
    f32x4 o[4] = {};
    kreg = *(const bf16x8*)&kbase[0];
    bf16x8 vreg = *(const bf16x8*)&vbase[0];
    for (int kt = 0; kt < SEQ; kt += 64) {
        __syncthreads();                            // prev tile's reads done
        *(bf16x8*)&Klds[srow*64 + swz8(srow, ssl)*8] = kreg;
        #pragma unroll
        for (int e = 0; e < 8; ++e) {               // transpose V: Vt[d][k]
            int d = ssl*8 + e;
            Vt[d*64 + swz8(d, srow>>3)*8 + (srow&7)] = vreg[e];
        }
        __syncthreads();
        if (kt + 64 < SEQ) {
            kreg = *(const bf16x8*)&kbase[(size_t)(kt+64)*D_MODEL];
            vreg = *(const bf16x8*)&vbase[(size_t)(kt+64)*D_MODEL];
        }
        f32x4 sc[4] = {};
        __builtin_amdgcn_s_setprio(1);
        #pragma unroll
        for (int kk = 0; kk < 2; ++kk)
            #pragma unroll
            for (int nf = 0; nf < 4; ++nf) {
                int krow = nf*16 + l15;
                bf16x8 kf = *(const bf16x8*)&Klds[krow*64 + swz8(krow, kk*4 + l4)*8];
                sc[nf] = MFMA16(qf[kk], kf, sc[nf]);
            }
        __builtin_amdgcn_s_setprio(0);
        size_t rowbase = ((size_t)bh*SEQ + qrow0 + wv*16 + l4*4)*SEQ + kt + l15;
        #pragma unroll
        for (int nf = 0; nf < 4; ++nf) {
            #pragma unroll
            for (int j = 0; j < 4; ++j) {
                float w = __expf(sc[nf][j]*0.125f - m[j]) * li[j];
                __builtin_nontemporal_store(w, &attn[rowbase + (size_t)j*SEQ + nf*16]);
                int prow = l4*4 + j, pcol = nf*16 + l15;
                Plds[wv*1024 + prow*64 + swz8(prow, pcol>>3)*8 + (pcol&7)] = f2bf(w);
            }
        }
        __builtin_amdgcn_s_setprio(1);
        #pragma unroll
        for (int kk = 0; kk < 2; ++kk) {
            bf16x8 pa = *(const bf16x8*)&Plds[wv*1024 + l15*64 + swz8(l15, kk*4 + l4)*8];
            #pragma unroll
            for (int nf = 0; nf < 4; ++nf) {
                int d = nf*16 + l15;
                bf16x8 vf = *(const bf16x8*)&Vt[d*64 + swz8(d, kk*4 + l4)*8];
                o[nf] = MFMA16(pa, vf, o[nf]);
            }
        }
        __builtin_amdgcn_s_setprio(0);
    }
    #pragma unroll
    for (int nf = 0; nf < 4; ++nf)
        #pragma unroll
        for (int j = 0; j < 4; ++j) {
            int qr = qrow0 + wv*16 + l4*4 + j;
            aob[(bs0 + qr)*D_MODEL + h*DH + nf*16 + l15] = f2bf(o[nf][j]);
        }
}

// ---------------------------------------------------------------------------
extern "C" void kernel_launch(void* const* d_in, const int* in_sizes, int n_in,
                              void* d_out, int out_size, void* d_ws, size_t ws_size,
                              hipStream_t stream)
{
    const float* query = (const float*)d_in[0];
    const float* key_  = (const float*)d_in[1];
    const float* value = (const float*)d_in[2];
    const float* Wq    = (const float*)d_in[3];
    const float* Wk    = (const float*)d_in[4];
    const float* Wv    = (const float*)d_in[5];
    const float* Wo    = (const float*)d_in[6];
    const float* bo    = (const float*)d_in[7];

    float* out  = (float*)d_out;
    float* attn = out + OUT_ELEMS;

    // ws layout (shorts): wqkv 3M | wob 1M | qb/kb/vb 12M | aob 4M | tab
    short* wqkv = (short*)d_ws;
    short* wob  = wqkv + (size_t)3*1048576;
    short* qkvb = wob  + (size_t)1048576;
    short* qb   = qkvb;
    short* kb   = qb + OUT_ELEMS;
    short* vb   = kb + OUT_ELEMS;
    short* aob  = vb + OUT_ELEMS;
    float* tab  = (float*)(aob + OUT_ELEMS);     // 2048*64 floats (512 KB)

    dim3 blk(256);

    hipLaunchKernelGGL(conv_w, dim3(4096), blk, 0, stream, Wq, Wk, Wv, Wo, wqkv, wob);
    hipLaunchKernelGGL(rope_table, dim3(256), blk, 0, stream, tab);
    hipLaunchKernelGGL(gemm_qkv, dim3(8, 32, 3), blk, 0, stream,
                       query, key_, value, wqkv, qkvb);
    hipLaunchKernelGGL(rope_apply, dim3(1024), blk, 0, stream, qb, kb, tab);
    hipLaunchKernelGGL(attn_fused, dim3(512), dim3(512), 0, stream,
                       qb, kb, vb, attn, aob);
    hipLaunchKernelGGL(gemm_out, dim3(8, 32), blk, 0, stream, aob, wob, bo, out);
}

// Round 6
// 319.813 us; speedup vs baseline: 4.6056x; 1.0405x over previous
//
#include <hip/hip_runtime.h>
#include <math.h>

#define D_MODEL 1024
#define SEQ     2048
#define NB      2
#define NH      16
#define DH      64
#define ROWS    (NB*SEQ)                  // 4096
#define OUT_ELEMS ((size_t)ROWS*D_MODEL)  // 4194304

typedef short bf16x8 __attribute__((ext_vector_type(8)));
typedef short bf16x4 __attribute__((ext_vector_type(4)));
typedef float f32x4  __attribute__((ext_vector_type(4)));

#define AS1 __attribute__((address_space(1)))
#define AS3 __attribute__((address_space(3)))

__device__ __forceinline__ float bf2f(short u){
    union{float f; unsigned v;} x; x.v = ((unsigned)(unsigned short)u) << 16; return x.f;
}
__device__ __forceinline__ short f2bf(float f){
    union{float f; unsigned v;} x; x.f = f;
    unsigned r = (x.v + 0x7FFF + ((x.v >> 16) & 1)) >> 16;   // RNE
    return (short)r;
}
__device__ __forceinline__ int swz8(int row, int slot){ return slot ^ ((row + (row>>3)) & 7); }

#define MFMA16(a,b,c) __builtin_amdgcn_mfma_f32_16x16x32_bf16((a),(b),(c),0,0,0)

// ---------------------------------------------------------------------------
// Convert all 4 weight matrices fp32->bf16 in one kernel.
// ---------------------------------------------------------------------------
__global__ __launch_bounds__(256) void conv_w(const float* __restrict__ Wq,
                                              const float* __restrict__ Wk,
                                              const float* __restrict__ Wv,
                                              const float* __restrict__ Wo,
                                              short* __restrict__ wqkv,
                                              short* __restrict__ wob)
{
    int i = blockIdx.x*256 + threadIdx.x;        // 1048576 float4 units
    int sel = i >> 18;                           // 262144 per weight
    int loc = i & 262143;
    const float* src = sel==0 ? Wq : sel==1 ? Wk : sel==2 ? Wv : Wo;
    short* dst = sel < 3 ? wqkv + (size_t)sel*1048576 : wob;
    float4 v = *(const float4*)&src[(size_t)loc*4];
    bf16x4 o = { f2bf(v.x), f2bf(v.y), f2bf(v.z), f2bf(v.w) };
    *(bf16x4*)&dst[(size_t)loc*4] = o;
}

// ---------------------------------------------------------------------------
// RoPE cos/sin table: tab[s*64 + j*2] = cos, +1 = sin  (s<2048, j<32).
// ---------------------------------------------------------------------------
__global__ __launch_bounds__(256) void rope_table(float* __restrict__ tab)
{
    int i = blockIdx.x*256 + threadIdx.x;        // 65536
    int j = i & 31, s = i >> 5;
    float ang = (float)s * exp2f(-(float)j * 0.41524101186092437f);
    float sn, cs; sincosf(ang, &sn, &cs);        // accurate large-arg reduction
    tab[(size_t)s*64 + j*2]     = cs;
    tab[(size_t)s*64 + j*2 + 1] = sn;
}

// ---------------------------------------------------------------------------
// Fused QKV projection.  z=0: Q (rope fused) -> qb row-major bf16.
//                        z=1: K (rope fused) -> kb row-major bf16.
//                        z=2: V -> vbt TRANSPOSED [bh][d][s] bf16.
// A fp32 reg-staged with fused bf16 convert; B (bf16) global_load_lds w=16.
// 128x128 tile, BK=32, 4 waves.  768 blocks.
// ---------------------------------------------------------------------------
__global__ __launch_bounds__(256) void gemm_qkv(const float* __restrict__ qx,
                                                const float* __restrict__ kx,
                                                const float* __restrict__ vx,
                                                const short* __restrict__ wqkv,
                                                const float* __restrict__ tab,
                                                short* __restrict__ qb,
                                                short* __restrict__ kb,
                                                short* __restrict__ vbt)
{
    const int z = blockIdx.z;
    const float* A = z==0 ? qx : z==1 ? kx : vx;
    const short* B = wqkv + (size_t)z*D_MODEL*D_MODEL;

    __shared__ __align__(16) short Alds[128*32];
    __shared__ __align__(16) short Blds[128*32];
    const int t = threadIdx.x, lane = t & 63, wid = t >> 6;
    const int m0 = blockIdx.y << 7, n0 = blockIdx.x << 7;
    const int wm = (wid >> 1) << 6, wn = (wid & 1) << 6;
    const int l15 = lane & 15, l4 = lane >> 4;

    f32x4 acc[4][4] = {};

    for (int k0 = 0; k0 < D_MODEL; k0 += 32) {
        float4 ar[4];
        #pragma unroll
        for (int u = 0; u < 4; ++u) {
            int id = u*256 + t;
            int row = id >> 3, c4 = id & 7;
            ar[u] = *(const float4*)&A[(size_t)(m0+row)*D_MODEL + k0 + c4*4];
        }
        __syncthreads();                   // prev iter's frag reads complete
        #pragma unroll
        for (int u = 0; u < 4; ++u) {
            int id = u*256 + t;
            int row = id >> 3, c4 = id & 7;
            bf16x4 a4 = { f2bf(ar[u].x), f2bf(ar[u].y), f2bf(ar[u].z), f2bf(ar[u].w) };
            *(bf16x4*)&Alds[row*32 + c4*4] = a4;
        }
        #pragma unroll
        for (int u = 0; u < 2; ++u) {
            int row = (wid*2 + u)*16 + (lane >> 2);
            int kc  = k0 + (lane & 3)*8;
            const short* gb = &B[(size_t)(n0 + row)*D_MODEL + kc];
            __builtin_amdgcn_global_load_lds((const AS1 unsigned*)gb,
                (AS3 unsigned*)&Blds[(wid*2 + u)*512], 16, 0, 0);
        }
        __syncthreads();                   // lgkm + vmcnt drain: tile ready
        bf16x8 af[4], bfr[4];
        #pragma unroll
        for (int mf = 0; mf < 4; ++mf)
            af[mf] = *(const bf16x8*)&Alds[(wm + mf*16 + l15)*32 + l4*8];
        #pragma unroll
        for (int nf = 0; nf < 4; ++nf)
            bfr[nf] = *(const bf16x8*)&Blds[(wn + nf*16 + l15)*32 + l4*8];
        #pragma unroll
        for (int mf = 0; mf < 4; ++mf)
            #pragma unroll
            for (int nf = 0; nf < 4; ++nf)
                acc[mf][nf] = MFMA16(af[mf], bfr[nf], acc[mf][nf]);
    }

    // C/D layout: col = lane&15, row = (lane>>4)*4 + j
    if (z < 2) {
        short* C = z==0 ? qb : kb;
        #pragma unroll
        for (int mf = 0; mf < 4; ++mf)
            #pragma unroll
            for (int j = 0; j < 4; ++j) {
                int row = m0 + wm + mf*16 + l4*4 + j;
                int s = row & (SEQ-1);
                #pragma unroll
                for (int p = 0; p < 2; ++p) {          // (d, d+32) pairs
                    int d31 = p*16 + l15;              // rotation index 0..31
                    float2 cs2 = *(const float2*)&tab[(size_t)s*64 + d31*2];
                    float x1 = acc[mf][p][j], x2 = acc[mf][p+2][j];
                    size_t rb = (size_t)row*D_MODEL + n0 + wn;
                    C[rb + p*16 + l15]       = f2bf(x1*cs2.x - x2*cs2.y);
                    C[rb + (p+2)*16 + l15]   = f2bf(x1*cs2.y + x2*cs2.x);
                }
            }
    } else {
        #pragma unroll
        for (int nf = 0; nf < 4; ++nf) {
            int col = n0 + wn + nf*16 + l15;
            int hh = col >> 6, d = col & 63;
            #pragma unroll
            for (int mf = 0; mf < 4; ++mf)
                #pragma unroll
                for (int j = 0; j < 4; ++j) {
                    int row = m0 + wm + mf*16 + l4*4 + j;
                    int b = row >> 11, s = row & (SEQ-1);
                    vbt[(((size_t)(b*NH + hh))*DH + d)*SEQ + s] = f2bf(acc[mf][nf][j]);
                }
        }
    }
}

// ---------------------------------------------------------------------------
// Pure-bf16 GEMM for the output projection: out = aob @ wob^T + bo (fp32 out).
// ---------------------------------------------------------------------------
__global__ __launch_bounds__(256) void gemm_out(const short* __restrict__ A,
                                                const short* __restrict__ B,
                                                const float* __restrict__ bias,
                                                float* __restrict__ Cout)
{
    __shared__ __align__(16) short Alds[128*32];
    __shared__ __align__(16) short Blds[128*32];
    const int t = threadIdx.x, lane = t & 63, wid = t >> 6;
    const int m0 = blockIdx.y << 7, n0 = blockIdx.x << 7;
    const int wm = (wid >> 1) << 6, wn = (wid & 1) << 6;
    const int l15 = lane & 15, l4 = lane >> 4;

    f32x4 acc[4][4] = {};

    for (int k0 = 0; k0 < D_MODEL; k0 += 32) {
        __syncthreads();
        #pragma unroll
        for (int u = 0; u < 2; ++u) {
            int row = (wid*2 + u)*16 + (lane >> 2);
            int kc  = k0 + (lane & 3)*8;
            const short* ga = &A[(size_t)(m0 + row)*D_MODEL + kc];
            const short* gb = &B[(size_t)(n0 + row)*D_MODEL + kc];
            __builtin_amdgcn_global_load_lds((const AS1 unsigned*)ga,
                (AS3 unsigned*)&Alds[(wid*2 + u)*512], 16, 0, 0);
            __builtin_amdgcn_global_load_lds((const AS1 unsigned*)gb,
                (AS3 unsigned*)&Blds[(wid*2 + u)*512], 16, 0, 0);
        }
        __syncthreads();
        bf16x8 af[4], bfr[4];
        #pragma unroll
        for (int mf = 0; mf < 4; ++mf)
            af[mf] = *(const bf16x8*)&Alds[(wm + mf*16 + l15)*32 + l4*8];
        #pragma unroll
        for (int nf = 0; nf < 4; ++nf)
            bfr[nf] = *(const bf16x8*)&Blds[(wn + nf*16 + l15)*32 + l4*8];
        #pragma unroll
        for (int mf = 0; mf < 4; ++mf)
            #pragma unroll
            for (int nf = 0; nf < 4; ++nf)
                acc[mf][nf] = MFMA16(af[mf], bfr[nf], acc[mf][nf]);
    }

    #pragma unroll
    for (int nf = 0; nf < 4; ++nf) {
        int col = n0 + wn + nf*16 + l15;
        float bv = bias[col];
        #pragma unroll
        for (int mf = 0; mf < 4; ++mf)
            #pragma unroll
            for (int j = 0; j < 4; ++j) {
                int row = m0 + wm + mf*16 + l4*4 + j;
                Cout[(size_t)row*D_MODEL + col] = acc[mf][nf][j] + bv;
            }
    }
}

// ---------------------------------------------------------------------------
// Fused two-loop flash attention, SWAPPED QK^T (mfma(K,Q) -> P[k][q], q=lane&15).
// Block = (b,h, 128 q-rows), 8 waves, wave owns 16 q-rows.
// Loop 1: online (m,l) with lane-local row reduction (2 shfl per tile).
// Loop 2: recompute scores, f32x4 NT weight stores, P->Plds bf16, MFMA PV.
// K staged row-major swizzled; V staged from pre-transposed vbt (b128 writes).
// ---------------------------------------------------------------------------
__global__ __launch_bounds__(512) void attn_fused(const short* __restrict__ qb,
                                                  const short* __restrict__ kb,
                                                  const short* __restrict__ vbt,
                                                  float* __restrict__ attn,
                                                  short* __restrict__ aob)
{
    __shared__ __align__(16) short Klds[64*64];
    __shared__ __align__(16) short Vt  [64*64];
    __shared__ __align__(16) short Plds[8*16*64];
    const int t = threadIdx.x, lane = t & 63, wv = t >> 6;
    const int bid = blockIdx.x;
    const int nb = (bid & 7)*64 + (bid >> 3);       // XCD swizzle (512 = 8*64)
    const int rb = nb & 15, bh = nb >> 4;           // bh = b*16+h
    const int h = bh & 15;
    const size_t bs0 = (size_t)(bh >> 4) * SEQ;
    const int qrow0 = rb << 7;
    const int l15 = lane & 15, l4 = lane >> 4;
    const int srow = t >> 3, ssl = t & 7;           // staging row/slot

    // Q fragments (B-operand: lane&15 = q-column of the score tile)
    bf16x8 qf[2];
    {
        int qrow = qrow0 + wv*16 + l15;
        const short* qp = &qb[(bs0 + qrow)*D_MODEL + h*DH + l4*8];
        qf[0] = *(const bf16x8*)&qp[0];
        qf[1] = *(const bf16x8*)&qp[32];
    }

    const short* kbase  = &kb[(bs0 + srow)*D_MODEL + h*DH + ssl*8];
    const short* vtbase = &vbt[((size_t)bh*DH + srow)*SEQ + ssl*8];

    float m = -1e30f, l = 0.f;

    // ---- loop 1: final row max + denom ---------------------------------
    bf16x8 kreg = *(const bf16x8*)&kbase[0];
    for (int kt = 0; kt < SEQ; kt += 64) {
        __syncthreads();                            // prev tile's reads done
        *(bf16x8*)&Klds[srow*64 + swz8(srow, ssl)*8] = kreg;
        __syncthreads();
        if (kt + 64 < SEQ)
            kreg = *(const bf16x8*)&kbase[(size_t)(kt+64)*D_MODEL];
        f32x4 sc[4] = {};
        __builtin_amdgcn_s_setprio(1);
        #pragma unroll
        for (int kk = 0; kk < 2; ++kk)
            #pragma unroll
            for (int nf = 0; nf < 4; ++nf) {
                int krow = nf*16 + l15;
                bf16x8 kf = *(const bf16x8*)&Klds[krow*64 + swz8(krow, kk*4 + l4)*8];
                sc[nf] = MFMA16(kf, qf[kk], sc[nf]);   // swapped: D[k][q]
            }
        __builtin_amdgcn_s_setprio(0);
        float tmax = -1e30f;
        #pragma unroll
        for (int nf = 0; nf < 4; ++nf)
            #pragma unroll
            for (int j = 0; j < 4; ++j)
                tmax = fmaxf(tmax, sc[nf][j]*0.125f);
        tmax = fmaxf(tmax, __shfl_xor(tmax, 16));
        tmax = fmaxf(tmax, __shfl_xor(tmax, 32));
        float mn = fmaxf(m, tmax);
        float ts = 0.f;
        #pragma unroll
        for (int nf = 0; nf < 4; ++nf)
            #pragma unroll
            for (int j = 0; j < 4; ++j)
                ts += __expf(sc[nf][j]*0.125f - mn);
        ts += __shfl_xor(ts, 16);
        ts += __shfl_xor(ts, 32);
        l = l*__expf(m - mn) + ts;
        m = mn;
    }
    const float li = 1.0f / l;

    // ---- loop 2: weights + PV -------------------------------------------
    f32x4 o[4] = {};
    kreg = *(const bf16x8*)&kbase[0];
    bf16x8 vreg = *(const bf16x8*)&vtbase[0];
    const size_t wrow = ((size_t)bh*SEQ + qrow0 + wv*16 + l15)*SEQ;
    for (int kt = 0; kt < SEQ; kt += 64) {
        __syncthreads();                            // prev tile's reads done
        *(bf16x8*)&Klds[srow*64 + swz8(srow, ssl)*8] = kreg;
        *(bf16x8*)&Vt  [srow*64 + swz8(srow, ssl)*8] = vreg;   // srow = d
        __syncthreads();
        if (kt + 64 < SEQ) {
            kreg = *(const bf16x8*)&kbase[(size_t)(kt+64)*D_MODEL];
            vreg = *(const bf16x8*)&vtbase[kt+64];
        }
        f32x4 sc[4] = {};
        __builtin_amdgcn_s_setprio(1);
        #pragma unroll
        for (int kk = 0; kk < 2; ++kk)
            #pragma unroll
            for (int nf = 0; nf < 4; ++nf) {
                int krow = nf*16 + l15;
                bf16x8 kf = *(const bf16x8*)&Klds[krow*64 + swz8(krow, kk*4 + l4)*8];
                sc[nf] = MFMA16(kf, qf[kk], sc[nf]);
            }
        __builtin_amdgcn_s_setprio(0);
        // weights: lane holds P[k = nf*16 + l4*4 + j][q = l15]
        #pragma unroll
        for (int nf = 0; nf < 4; ++nf) {
            float w0 = __expf(sc[nf][0]*0.125f - m) * li;
            float w1 = __expf(sc[nf][1]*0.125f - m) * li;
            float w2 = __expf(sc[nf][2]*0.125f - m) * li;
            float w3 = __expf(sc[nf][3]*0.125f - m) * li;
            f32x4 wv4 = { w0, w1, w2, w3 };
            __builtin_nontemporal_store(wv4,
                (f32x4*)&attn[wrow + kt + nf*16 + l4*4]);
            #pragma unroll
            for (int j = 0; j < 4; ++j) {
                int k = nf*16 + l4*4 + j;
                Plds[wv*1024 + l15*64 + swz8(l15, k>>3)*8 + (k&7)] =
                    f2bf(j==0 ? w0 : j==1 ? w1 : j==2 ? w2 : w3);
            }
        }
        __builtin_amdgcn_s_setprio(1);
        #pragma unroll
        for (int kk = 0; kk < 2; ++kk) {
            bf16x8 pa = *(const bf16x8*)&Plds[wv*1024 + l15*64 + swz8(l15, kk*4 + l4)*8];
            #pragma unroll
            for (int nf = 0; nf < 4; ++nf) {
                int d = nf*16 + l15;
                bf16x8 vf = *(const bf16x8*)&Vt[d*64 + swz8(d, kk*4 + l4)*8];
                o[nf] = MFMA16(pa, vf, o[nf]);
            }
        }
        __builtin_amdgcn_s_setprio(0);
    }
    #pragma unroll
    for (int nf = 0; nf < 4; ++nf)
        #pragma unroll
        for (int j = 0; j < 4; ++j) {
            int qr = qrow0 + wv*16 + l4*4 + j;
            aob[(bs0 + qr)*D_MODEL + h*DH + nf*16 + l15] = f2bf(o[nf][j]);
        }
}

// ---------------------------------------------------------------------------
extern "C" void kernel_launch(void* const* d_in, const int* in_sizes, int n_in,
                              void* d_out, int out_size, void* d_ws, size_t ws_size,
                              hipStream_t stream)
{
    const float* query = (const float*)d_in[0];
    const float* key_  = (const float*)d_in[1];
    const float* value = (const float*)d_in[2];
    const float* Wq    = (const float*)d_in[3];
    const float* Wk    = (const float*)d_in[4];
    const float* Wv    = (const float*)d_in[5];
    const float* Wo    = (const float*)d_in[6];
    const float* bo    = (const float*)d_in[7];

    float* out  = (float*)d_out;
    float* attn = out + OUT_ELEMS;

    // ws (shorts): wqkv 3M | wob 1M | qb 4M | kb 4M | vbt 4M | aob 4M | tab
    short* wqkv = (short*)d_ws;
    short* wob  = wqkv + (size_t)3*1048576;
    short* qb   = wob  + (size_t)1048576;
    short* kb   = qb + OUT_ELEMS;
    short* vbt  = kb + OUT_ELEMS;                // [bh=32][d=64][s=2048]
    short* aob  = vbt + OUT_ELEMS;
    float* tab  = (float*)(aob + OUT_ELEMS);     // 2048*64 floats (512 KB)

    dim3 blk(256);

    hipLaunchKernelGGL(conv_w, dim3(4096), blk, 0, stream, Wq, Wk, Wv, Wo, wqkv, wob);
    hipLaunchKernelGGL(rope_table, dim3(256), blk, 0, stream, tab);
    hipLaunchKernelGGL(gemm_qkv, dim3(8, 32, 3), blk, 0, stream,
                       query, key_, value, wqkv, tab, qb, kb, vbt);
    hipLaunchKernelGGL(attn_fused, dim3(512), dim3(512), 0, stream,
                       qb, kb, vbt, attn, aob);
    hipLaunchKernelGGL(gemm_out, dim3(8, 32), blk, 0, stream, aob, wob, bo, out);
}